// Round 9
// baseline (97.888 us; speedup 1.0000x reference)
//
#include <hip/hip_runtime.h>

// Problem constants (from reference setup_inputs)
#define Bn 8
#define Nn 128
#define Fdim 32     // input feature dim F
#define Sdim 8      // edge feature dim S
#define Hdim 32     // kernel-network hidden width H
#define Fout 32     // output channels F_

#define QP 40       // bf16 row pitch for per-wave hT/nT slices: 80B (16B-aligned, 2-way banks)

typedef float  f32x4  __attribute__((ext_vector_type(4)));
typedef short  bf16x8 __attribute__((ext_vector_type(8)));

__device__ __forceinline__ unsigned short f2bf(float x) {
    union { float f; unsigned u; } v; v.f = x;
    return (unsigned short)((v.u + 0x7FFFu + ((v.u >> 16) & 1u)) >> 16);
}
__device__ __forceinline__ unsigned pack2(float lo, float hi) {
    return (unsigned)f2bf(lo) | ((unsigned)f2bf(hi) << 16);
}

// One block per (a,b); 256 threads; wave q owns i-quarter [q*32, q*32+32).
// Phases: [zero Tacc, B0] -> wave-private {inv-part, nT stage+q', hT stage, MFMA K=32,
// ds_add into Tacc} (NO inter-wave sync) -> B1 -> epilogue (Wout contraction).
// out[a,b,c] = inv*( sum_{h,f} T'[h,f]*Wout[h,c*32+f] + sum_f q'[f]*bout[c*32+f] ) + bias[c]
__global__ __launch_bounds__(256, 6) void ecc_kernel(
    const float* __restrict__ nf,    // (B,N,F)
    const float* __restrict__ fltr,  // (B,N,N)
    const float* __restrict__ ef,    // (B,N,N,S)
    const float* __restrict__ W0,    // (S,H)
    const float* __restrict__ b0,    // (H)
    const float* __restrict__ Wout,  // (H, F_*F)
    const float* __restrict__ bout,  // (F_*F)
    const float* __restrict__ bias,  // (F_)
    float* __restrict__ out)         // (B,N,F_)
{
    __shared__ __align__(16) unsigned short hT[4 * Hdim * QP]; // 10.2 KB: per-wave h^T[h][ki] bf16
    __shared__ __align__(16) unsigned short nT[4 * Fdim * QP]; // 10.2 KB: per-wave nf^T[f][ki] bf16
    __shared__ __align__(16) float Tacc[1056];                 // 4.2 KB: T'[h][f] (+ q' at 1024..1055)
    __shared__ float qsum[4];

    const int t     = threadIdx.x;
    const int blk   = blockIdx.x;       // a*N + b
    const int a     = blk >> 7;
    const int w     = t >> 6;           // wave / i-quarter
    const int l     = t & 63;
    const int lane5 = l & 31;           // h (hT) / f (nT)
    const int ihalf = l >> 5;           // 16-i half within the quarter
    const int i0    = w * 32;

    const float* __restrict__ nfa  = nf   + (size_t)a   * (Nn * Fdim);
    const float* __restrict__ frow = fltr + (size_t)blk * Nn;
    const float* __restrict__ erow = ef   + (size_t)blk * (Nn * Sdim);

    // ---- W0 column + b0 in registers ----
    float w0r[Sdim];
    #pragma unroll
    for (int s = 0; s < Sdim; ++s) w0r[s] = W0[s * Hdim + lane5];
    const float b0r = b0[lane5];

    // ---- B0: zero the ds_add accumulator ----
    {
        f32x4 z = {0.f, 0.f, 0.f, 0.f};
        ((f32x4*)Tacc)[t < 264 ? t : 0] = z;     // e 0..255
        if (t < 8) ((f32x4*)Tacc)[256 + t] = z;  // e 256..263
    }
    __syncthreads();                             // B0

    // ======== wave-private phase (no inter-wave sync) ========

    // inv partial: sum of this quarter's fltr values
    {
        float s = frow[i0 + lane5];
        #pragma unroll
        for (int off = 16; off > 0; off >>= 1) s += __shfl_down(s, off, 32);
        if (l == 0) qsum[w] = s;
    }

    // nf^T staging (bf16, wave slice) fused with q' partial
    {
        float x[16], qpart = 0.f;
        #pragma unroll
        for (int k = 0; k < 16; ++k) {
            const int i = i0 + ihalf * 16 + k;
            x[k] = nfa[i * Fdim + lane5];        // coalesced 128B per 32 lanes
            qpart += frow[i] * x[k];
        }
        unsigned* nd = (unsigned*)&nT[(size_t)(w * Fdim + lane5) * QP];
        #pragma unroll
        for (int k = 0; k < 16; k += 2) nd[ihalf * 8 + (k >> 1)] = pack2(x[k], x[k + 1]);
        qpart += __shfl_xor(qpart, 32);
        if (ihalf == 0) atomicAdd(&Tacc[1024 + lane5], qpart);   // ds_add_f32
    }

    // h^T staging: hT[h][ki] = bf16( relu(ef[i,:]@W0+b0)[h] * fltr[i] )
    {
        unsigned* hd = (unsigned*)&hT[(size_t)(w * Hdim + lane5) * QP];
        #pragma unroll
        for (int k = 0; k < 16; k += 2) {
            const int i = i0 + ihalf * 16 + k;
            const float4 e0a = *(const float4*)(erow + i * Sdim);
            const float4 e0b = *(const float4*)(erow + i * Sdim + 4);
            const float4 e1a = *(const float4*)(erow + i * Sdim + 8);
            const float4 e1b = *(const float4*)(erow + i * Sdim + 12);
            float a0 = b0r, a1 = b0r;
            a0 += e0a.x * w0r[0] + e0a.y * w0r[1] + e0a.z * w0r[2] + e0a.w * w0r[3];
            a0 += e0b.x * w0r[4] + e0b.y * w0r[5] + e0b.z * w0r[6] + e0b.w * w0r[7];
            a1 += e1a.x * w0r[0] + e1a.y * w0r[1] + e1a.z * w0r[2] + e1a.w * w0r[3];
            a1 += e1b.x * w0r[4] + e1b.y * w0r[5] + e1b.z * w0r[6] + e1b.w * w0r[7];
            const float h0 = fmaxf(a0, 0.0f) * frow[i];
            const float h1 = fmaxf(a1, 0.0f) * frow[i + 1];
            hd[ihalf * 8 + (k >> 1)] = pack2(h0, h1);
        }
    }

    // within-wave LDS write->read ordering (defensive; DS is in-order per wave)
    asm volatile("s_waitcnt lgkmcnt(0)" ::: "memory");
    __builtin_amdgcn_sched_barrier(0);

    // wave-local MFMA: 2x2 tiles of T over K=32 (this wave's i-quarter)
    {
        const int lr = l & 15, lg = l >> 4;
        f32x4 acc[2][2];
        #pragma unroll
        for (int mt = 0; mt < 2; ++mt)
            #pragma unroll
            for (int nt = 0; nt < 2; ++nt) acc[mt][nt] = (f32x4){0.f, 0.f, 0.f, 0.f};
        #pragma unroll
        for (int mt = 0; mt < 2; ++mt) {
            const bf16x8 av = *(const bf16x8*)&hT[(size_t)(w * Hdim + mt * 16 + lr) * QP + lg * 8];
            #pragma unroll
            for (int nt = 0; nt < 2; ++nt) {
                const bf16x8 bv = *(const bf16x8*)&nT[(size_t)(w * Fdim + nt * 16 + lr) * QP + lg * 8];
                acc[mt][nt] = __builtin_amdgcn_mfma_f32_16x16x32_bf16(av, bv, acc[mt][nt], 0, 0, 0);
            }
        }
        // C/D layout: col = lane&15, row = (lane>>4)*4 + reg  [m89-verified]
        #pragma unroll
        for (int mt = 0; mt < 2; ++mt)
            #pragma unroll
            for (int nt = 0; nt < 2; ++nt)
                #pragma unroll
                for (int r = 0; r < 4; ++r)
                    atomicAdd(&Tacc[(mt * 16 + lg * 4 + r) * Fdim + nt * 16 + lr],
                              acc[mt][nt][r]);                    // ds_add_f32
    }
    __syncthreads();                             // B1

    // ---- epilogue: out[c] = inv*(Tacc.Wout + q'.bout) + bias ----
    {
        const float inv = 1.0f / fmaxf(qsum[0] + qsum[1] + qsum[2] + qsum[3], 1e-11f);
        const int c = t >> 3, f4 = t & 7;
        const float* wbase = Wout + (size_t)c * Fdim + f4 * 4;
        float partial = 0.f;
        #pragma unroll
        for (int h = 0; h < Hdim; ++h) {
            const float4 wv = *(const float4*)(wbase + (size_t)h * (Fout * Fdim));
            const float4 tv = *(const float4*)&Tacc[h * Fdim + f4 * 4];
            partial += tv.x * wv.x + tv.y * wv.y + tv.z * wv.z + tv.w * wv.w;
        }
        {
            const float4 bv = *(const float4*)(bout + (size_t)c * Fdim + f4 * 4);
            const float4 qv = *(const float4*)&Tacc[1024 + f4 * 4];
            partial += qv.x * bv.x + qv.y * bv.y + qv.z * bv.z + qv.w * bv.w;
        }
        partial += __shfl_down(partial, 4, 8);
        partial += __shfl_down(partial, 2, 8);
        partial += __shfl_down(partial, 1, 8);
        if (f4 == 0)
            out[(size_t)blk * Fout + c] = partial * inv + bias[c];
    }
}

extern "C" void kernel_launch(void* const* d_in, const int* in_sizes, int n_in,
                              void* d_out, int out_size, void* d_ws, size_t ws_size,
                              hipStream_t stream) {
    const float* nf   = (const float*)d_in[0];
    const float* fltr = (const float*)d_in[1];
    const float* ef   = (const float*)d_in[2];
    const float* W0   = (const float*)d_in[3];
    const float* b0   = (const float*)d_in[4];
    const float* Wout = (const float*)d_in[5];
    const float* bout = (const float*)d_in[6];
    const float* bias = (const float*)d_in[7];
    float* out = (float*)d_out;

    ecc_kernel<<<dim3(Bn * Nn), dim3(256), 0, stream>>>(
        nf, fltr, ef, W0, b0, Wout, bout, bias, out);
}